// Round 2
// baseline (233.276 us; speedup 1.0000x reference)
//
#include <hip/hip_runtime.h>
#include <hip/hip_fp16.h>

#define NF 128    // feature dim, fixed by the problem
#define KC 64     // edge chunks
#define NPART 4   // node partitions (N/4 ints must fit LDS: 12500*4B = 50KB)
#define NPMAX 12544

typedef _Float16 half8  __attribute__((ext_vector_type(8)));
typedef _Float16 half4v __attribute__((ext_vector_type(4)));
typedef float    floatx4 __attribute__((ext_vector_type(4)));

// ---------------- count2: LDS histogram per (chunk, partition) -------------------
__global__ __launch_bounds__(512) void count2_k(
    const int* __restrict__ dst, unsigned char* __restrict__ pcnt,
    int E, int N, int Ec)
{
    __shared__ int lcnt[NPMAX];
    const int p = blockIdx.x & 3, c = blockIdx.x >> 2;
    const int Np = (N + 3) >> 2;
    const int lo = p * Np, hi = min(lo + Np, N);
    const int sz = hi - lo;
    for (int i = threadIdx.x; i < sz; i += 512) lcnt[i] = 0;
    __syncthreads();

    const int e0 = c * Ec, e1 = min(e0 + Ec, E);
    for (int e = e0 + (int)threadIdx.x * 4; e + 3 < e1; e += 512 * 4) {
        int4 d = *(const int4*)(dst + e);
        if (d.x >= lo && d.x < hi) atomicAdd(&lcnt[d.x - lo], 1);
        if (d.y >= lo && d.y < hi) atomicAdd(&lcnt[d.y - lo], 1);
        if (d.z >= lo && d.z < hi) atomicAdd(&lcnt[d.z - lo], 1);
        if (d.w >= lo && d.w < hi) atomicAdd(&lcnt[d.w - lo], 1);
    }
    int rem0 = e0 + ((e1 - e0) & ~3);
    for (int e = rem0 + (int)threadIdx.x; e < e1; e += 512) {
        int d = dst[e];
        if (d >= lo && d < hi) atomicAdd(&lcnt[d - lo], 1);
    }
    __syncthreads();
    for (int i = threadIdx.x; i < sz; i += 512)
        pcnt[(size_t)c * N + lo + i] = (unsigned char)lcnt[i];
}

// ---------------- pscan2 (+fused W-transpose) ------------------------------------
__global__ __launch_bounds__(256) void pscan2_k(
    unsigned char* __restrict__ pcnt, float* __restrict__ dinv,
    int* __restrict__ rowptr, int* __restrict__ blocksum, int n, int N, int nb,
    const float* __restrict__ W1, const float* __restrict__ W2,
    __half* __restrict__ WT1, __half* __restrict__ WT2)
{
    if ((int)blockIdx.x >= nb) {
        int idx = ((int)blockIdx.x - nb) * 256 + threadIdx.x;   // 0..32767
        const float* W = (idx < 16384) ? W1 : W2;
        __half* WT     = (idx < 16384) ? WT1 : WT2;
        int j = idx & 16383;
        int nn = j & 127, k = j >> 7;
        WT[nn * NF + k] = __float2half(W[k * NF + nn]);
        return;
    }
    __shared__ int sm[256];
    int tid = threadIdx.x;
    int bin = blockIdx.x * 256 + tid;
    int total = 0;
    if (bin < n) {
        #pragma unroll 4
        for (int c = 0; c < KC; c++) {
            size_t o = (size_t)c * N + bin;
            int v = pcnt[o];
            pcnt[o] = (unsigned char)total;   // exclusive chunk prefix (coff)
            total += v;
        }
        dinv[bin] = rsqrtf((float)total + 1.0f);  // +1 = self-loop
    }
    sm[tid] = total;
    __syncthreads();
    #pragma unroll
    for (int d = 1; d < 256; d <<= 1) {
        int t = (tid >= d) ? sm[tid - d] : 0;
        __syncthreads();
        sm[tid] += t;
        __syncthreads();
    }
    if (bin < n) rowptr[bin] = sm[tid] - total;    // local exclusive prefix
    if (tid == 255) blocksum[blockIdx.x] = sm[255];
}

// ---------------- MFMA GEMM body (512 threads, 128 rows/block) -------------------
template<bool F32IN>
__device__ __forceinline__ void gemm_body512(
    const void* __restrict__ Xv, const __half* __restrict__ WT,
    const float* __restrict__ dinv, __half* __restrict__ out, int M, int bid,
    __half (*wlds)[136])
{
    const int tid = threadIdx.x;
    {   // stage WT (128x128 halves): 4 threads/row, 32 halves each
        int r = tid >> 2;
        int c0 = (tid & 3) * 32;
        const half8* s = (const half8*)(WT + (size_t)r * NF + c0);
        half8* d = (half8*)&wlds[r][c0];
        #pragma unroll
        for (int j = 0; j < 4; j++) d[j] = s[j];
    }
    __syncthreads();

    const int wave = tid >> 6, lane = tid & 63;
    const int quad = lane >> 4, l15 = lane & 15;
    const int rowA = bid * 128 + wave * 16 + l15;
    const int rowc = (rowA < M) ? rowA : (M - 1);

    half8 afr[4];
    if (F32IN) {
        const float* X = (const float*)Xv;
        #pragma unroll
        for (int kc = 0; kc < 4; kc++) {
            const floatx4* p = (const floatx4*)(X + (size_t)rowc * NF + kc * 32 + quad * 8);
            floatx4 u = p[0], v = p[1];
            half8 a;
            a[0] = (_Float16)u[0]; a[1] = (_Float16)u[1];
            a[2] = (_Float16)u[2]; a[3] = (_Float16)u[3];
            a[4] = (_Float16)v[0]; a[5] = (_Float16)v[1];
            a[6] = (_Float16)v[2]; a[7] = (_Float16)v[3];
            afr[kc] = a;
        }
    } else {
        const __half* X = (const __half*)Xv;
        #pragma unroll
        for (int kc = 0; kc < 4; kc++)
            afr[kc] = *(const half8*)(X + (size_t)rowc * NF + kc * 32 + quad * 8);
    }

    floatx4 acc[8];
    #pragma unroll
    for (int ct = 0; ct < 8; ct++) { floatx4 z = {0.f, 0.f, 0.f, 0.f}; acc[ct] = z; }

    #pragma unroll
    for (int kc = 0; kc < 4; kc++) {
        #pragma unroll
        for (int ct = 0; ct < 8; ct++) {
            half8 b = *(const half8*)&wlds[ct * 16 + l15][kc * 32 + quad * 8];
            acc[ct] = __builtin_amdgcn_mfma_f32_16x16x32_f16(afr[kc], b, acc[ct], 0, 0, 0);
        }
    }

    const int orow0 = bid * 128 + wave * 16 + quad * 4;
    #pragma unroll
    for (int r = 0; r < 4; r++) {
        int orow = orow0 + r;
        if (orow < M) {
            float s = dinv[orow];
            #pragma unroll
            for (int ct = 0; ct < 8; ct++)
                out[(size_t)orow * NF + ct * 16 + l15] = __float2half(acc[ct][r] * s);
        }
    }
}

// ---------------- mid_k: fused gemm1 + fill (+add_off) ---------------------------
__global__ __launch_bounds__(512) void mid_k(
    const int* __restrict__ src, const int* __restrict__ dst,
    const int* __restrict__ rowptr, const unsigned char* __restrict__ coff,
    const int* __restrict__ blocksum, int* __restrict__ rowptr2,
    int* __restrict__ csr, int E, int N, int Ec, int nb,
    const float* __restrict__ X, const __half* __restrict__ WT,
    const float* __restrict__ dinv, __half* __restrict__ H, int GB2)
{
    __shared__ __align__(16) char smem[NPMAX * 4 + 1024];   // 51.2KB union
    const int tid = threadIdx.x;
    if ((int)blockIdx.x < GB2) {
        gemm_body512<true>(X, WT, dinv, H, N, blockIdx.x, (__half(*)[136])smem);
        return;
    }
    int* lcur = (int*)smem;
    int* pref = (int*)(smem + NPMAX * 4);

    const int b = blockIdx.x - GB2;
    const int p = b & 3, c = b >> 2;
    const int Np = (N + 3) >> 2;
    const int lo = p * Np, hi = min(lo + Np, N);
    const int sz = hi - lo;

    // exclusive prefix of blocksum[0..nb) in pref
    int v = (tid < nb) ? blocksum[tid] : 0;
    if (tid < 256) pref[tid] = v;
    __syncthreads();
    #pragma unroll
    for (int d = 1; d < 256; d <<= 1) {
        int t = (tid < 256 && tid >= d) ? pref[tid - d] : 0;
        __syncthreads();
        if (tid < 256) pref[tid] += t;
        __syncthreads();
    }
    if (tid < 256) pref[tid] -= v;
    __syncthreads();

    for (int i = tid; i < sz; i += 512) {
        int bin = lo + i;
        int r = rowptr[bin] + pref[bin >> 8] + (int)coff[(size_t)c * N + bin];
        lcur[i] = r;
        if (c == 0) rowptr2[bin] = r;
    }
    if (c == 0 && p == 0 && tid == 0) rowptr2[N] = E;
    __syncthreads();

    const int e0 = c * Ec, e1 = min(e0 + Ec, E);
    for (int e = e0 + tid * 4; e + 3 < e1; e += 512 * 4) {
        int4 d = *(const int4*)(dst + e);
        int4 s = *(const int4*)(src + e);
        if (d.x >= lo && d.x < hi) csr[atomicAdd(&lcur[d.x - lo], 1)] = s.x;
        if (d.y >= lo && d.y < hi) csr[atomicAdd(&lcur[d.y - lo], 1)] = s.y;
        if (d.z >= lo && d.z < hi) csr[atomicAdd(&lcur[d.z - lo], 1)] = s.z;
        if (d.w >= lo && d.w < hi) csr[atomicAdd(&lcur[d.w - lo], 1)] = s.w;
    }
    int rem0 = e0 + ((e1 - e0) & ~3);
    for (int e = rem0 + tid; e < e1; e += 512) {
        int d = dst[e];
        if (d >= lo && d < hi) csr[atomicAdd(&lcur[d - lo], 1)] = src[e];
    }
}

// ---------------- bsort: sort each CSR bucket by src (locality only) -------------
// Wave per node, 64-lane in-register bitonic sort. Buckets are Poisson(16)
// (max ~45 < 64) so one group covers a node; cnt>64 groups sort independently
// (partial order is fine — sorting is purely a locality hint for the gather).
__global__ __launch_bounds__(256) void bsort_k(
    const int* __restrict__ rowptr, int* __restrict__ csr, int n)
{
    int wave = threadIdx.x >> 6, lane = threadIdx.x & 63;
    int node = blockIdx.x * 4 + wave;
    if (node >= n) return;
    int base = rowptr[node], cnt = rowptr[node + 1] - base;
    for (int off = 0; off < cnt; off += 64) {
        int m = min(64, cnt - off);
        if (m <= 1) break;
        int v = (lane < m) ? csr[base + off + lane] : 0x7fffffff;
        #pragma unroll
        for (int k = 2; k <= 64; k <<= 1) {
            #pragma unroll
            for (int j = k >> 1; j >= 1; j >>= 1) {
                int pv = __shfl_xor(v, j, 64);
                bool up = ((lane & k) == 0);
                bool mn = (((lane & j) == 0) == up);
                v = mn ? min(v, pv) : max(v, pv);
            }
        }
        if (lane < m) csr[base + off + lane] = v;
    }
}

// ---------------- gather4s: 4 nodes per wave, chunk-major sweep ------------------
// Buckets are sorted by src; the wave processes 2 edges of EACH of its 4 nodes
// per round, so its read position sweeps src-space monotonically over ~10 rounds.
// All resident waves sweep together -> instantaneous working set ~2-3MB (fits
// per-XCD L2) instead of the whole 12.8MB table. unroll-2 keeps ~8 loads deep.
__device__ __forceinline__ void gather4s(
    const half4v* __restrict__ hs4, const int* __restrict__ csr,
    const int* __restrict__ rowptr, int node0, int n,
    int eg, int fl, int lane, floatx4 acc[4])
{
    int base[4], cc[4], rc[4], idx[4];
    int maxc = 0;
    #pragma unroll
    for (int k = 0; k < 4; k++) {
        int nd = node0 + k;
        int b0 = 0, c0 = 0;
        if (nd < n) { b0 = rowptr[nd]; c0 = rowptr[nd + 1] - b0; }
        base[k] = b0; rc[k] = c0; cc[k] = min(c0, 64);
        maxc = max(maxc, cc[k]);
    }
    #pragma unroll
    for (int k = 0; k < 4; k++)
        idx[k] = (lane < cc[k]) ? __builtin_nontemporal_load(&csr[base[k] + lane]) : 0;

    #pragma unroll
    for (int k = 0; k < 4; k++) { floatx4 z = {0.f, 0.f, 0.f, 0.f}; acc[k] = z; }

    if (eg == 0) {   // self-loops
        #pragma unroll
        for (int k = 0; k < 4; k++) {
            int nd = node0 + k;
            if (nd < n) {
                half4v s = hs4[(size_t)nd * 32 + fl];
                acc[k][0] += (float)s[0]; acc[k][1] += (float)s[1];
                acc[k][2] += (float)s[2]; acc[k][3] += (float)s[3];
            }
        }
    }

    const int rmax = (maxc + 1) >> 1;
    #pragma unroll 2
    for (int s = 0; s < rmax; s++) {
        const int e2 = s * 2;
        #pragma unroll
        for (int k = 0; k < 4; k++) {
            if (e2 < cc[k]) {
                int si = __shfl(idx[k], min(e2 + eg, cc[k] - 1), 64);
                half4v v = hs4[(size_t)si * 32 + fl];
                if (e2 + eg < cc[k]) {
                    acc[k][0] += (float)v[0]; acc[k][1] += (float)v[1];
                    acc[k][2] += (float)v[2]; acc[k][3] += (float)v[3];
                }
            }
        }
    }

    // tails (cnt > 64): vanishingly rare at Poisson(16); simple unit-2 walk
    #pragma unroll
    for (int k = 0; k < 4; k++) {
        for (int off = 64; off < rc[k]; off += 64) {
            int m = min(64, rc[k] - off);
            int id2 = (lane < m) ? __builtin_nontemporal_load(&csr[base[k] + off + lane]) : 0;
            for (int j = 0; j < m; j += 2) {
                int si = __shfl(id2, min(j + eg, m - 1), 64);
                half4v v = hs4[(size_t)si * 32 + fl];
                if (j + eg < m) {
                    acc[k][0] += (float)v[0]; acc[k][1] += (float)v[1];
                    acc[k][2] += (float)v[2]; acc[k][3] += (float)v[3];
                }
            }
        }
    }

    #pragma unroll
    for (int k = 0; k < 4; k++) {
        #pragma unroll
        for (int q = 0; q < 4; q++)
            acc[k][q] += __shfl_xor(acc[k][q], 32, 64);
    }
}

// ---------------- aggmm: fused agg(layer1) + gemm2, sweep gather ----------------
__global__ __launch_bounds__(256) void aggmm_k(
    const __half* __restrict__ hs, const int* __restrict__ rowptr,
    const int* __restrict__ csr, const float* __restrict__ dinv,
    const float* __restrict__ bias, const __half* __restrict__ WT,
    __half* __restrict__ Hout, int n)
{
    __shared__ __half alds[16][136];
    const int tid = threadIdx.x;
    const int wave = tid >> 6, lane = tid & 63;
    const int eg = lane >> 5, fl = lane & 31;
    const int nb0 = blockIdx.x * 16;
    const int node0 = nb0 + wave * 4;

    floatx4 acc[4];
    gather4s((const half4v*)hs, csr, rowptr, node0, n, eg, fl, lane, acc);

    if (eg == 0) {
        #pragma unroll
        for (int k = 0; k < 4; k++) {
            int node = node0 + k;
            half4v h;
            if (node < n) {
                float dv = dinv[node];
                h[0] = (_Float16)fmaxf(dv * acc[k][0] + bias[fl * 4 + 0], 0.f);
                h[1] = (_Float16)fmaxf(dv * acc[k][1] + bias[fl * 4 + 1], 0.f);
                h[2] = (_Float16)fmaxf(dv * acc[k][2] + bias[fl * 4 + 2], 0.f);
                h[3] = (_Float16)fmaxf(dv * acc[k][3] + bias[fl * 4 + 3], 0.f);
            } else {
                h[0] = (_Float16)0.f; h[1] = (_Float16)0.f;
                h[2] = (_Float16)0.f; h[3] = (_Float16)0.f;
            }
            *(half4v*)&alds[wave * 4 + k][fl * 4] = h;
        }
    }
    __syncthreads();

    // wave w computes output column-tiles ct = {2w, 2w+1} for all 16 rows
    const int quad = lane >> 4, l15 = lane & 15;
    half8 afr[4];
    #pragma unroll
    for (int kc = 0; kc < 4; kc++)
        afr[kc] = *(const half8*)&alds[l15][kc * 32 + quad * 8];

    floatx4 acc0 = {0.f, 0.f, 0.f, 0.f};
    floatx4 acc1 = {0.f, 0.f, 0.f, 0.f};
    const int ct0 = wave * 2, ct1 = wave * 2 + 1;
    #pragma unroll
    for (int kc = 0; kc < 4; kc++) {
        half8 b0 = *(const half8*)(WT + (size_t)(ct0 * 16 + l15) * NF + kc * 32 + quad * 8);
        half8 b1 = *(const half8*)(WT + (size_t)(ct1 * 16 + l15) * NF + kc * 32 + quad * 8);
        acc0 = __builtin_amdgcn_mfma_f32_16x16x32_f16(afr[kc], b0, acc0, 0, 0, 0);
        acc1 = __builtin_amdgcn_mfma_f32_16x16x32_f16(afr[kc], b1, acc1, 0, 0, 0);
    }

    #pragma unroll
    for (int r = 0; r < 4; r++) {
        int row = quad * 4 + r;
        int node = nb0 + row;
        if (node < n) {
            float s = dinv[node];
            Hout[(size_t)node * NF + ct0 * 16 + l15] = __float2half(acc0[r] * s);
            Hout[(size_t)node * NF + ct1 * 16 + l15] = __float2half(acc1[r] * s);
        }
    }
}

// ---------------- agg4: final aggregate (fp32 out), sweep gather -----------------
__global__ __launch_bounds__(256) void agg4_k(
    const __half* __restrict__ hs, const int* __restrict__ rowptr,
    const int* __restrict__ csr, const float* __restrict__ dinv,
    const float* __restrict__ bias, float* __restrict__ outf, int n)
{
    const int tid = threadIdx.x;
    const int wave = tid >> 6, lane = tid & 63;
    const int eg = lane >> 5, fl = lane & 31;
    const int node0 = blockIdx.x * 16 + wave * 4;

    floatx4 acc[4];
    gather4s((const half4v*)hs, csr, rowptr, node0, n, eg, fl, lane, acc);

    if (eg == 0) {
        #pragma unroll
        for (int k = 0; k < 4; k++) {
            int node = node0 + k;
            if (node < n) {
                float dv = dinv[node];
                floatx4 w;
                w[0] = dv * acc[k][0] + bias[fl * 4 + 0];
                w[1] = dv * acc[k][1] + bias[fl * 4 + 1];
                w[2] = dv * acc[k][2] + bias[fl * 4 + 2];
                w[3] = dv * acc[k][3] + bias[fl * 4 + 3];
                *(floatx4*)(outf + (size_t)node * NF + fl * 4) = w;
            }
        }
    }
}

// ---------------- launch ----------------

extern "C" void kernel_launch(void* const* d_in, const int* in_sizes, int n_in,
                              void* d_out, int out_size, void* d_ws, size_t ws_size,
                              hipStream_t stream) {
    const float* x  = (const float*)d_in[0];
    const int*   ei = (const int*)d_in[1];
    const float* W1 = (const float*)d_in[2];
    const float* b1 = (const float*)d_in[3];
    const float* W2 = (const float*)d_in[4];
    const float* b2 = (const float*)d_in[5];
    float* out = (float*)d_out;

    const int N = in_sizes[0] / NF;   // 50000
    const int E = in_sizes[1] / 2;    // 800000
    const int* src = ei;
    const int* dst = ei + E;

    char* ws = (char*)d_ws;
    size_t off = 0;
    auto alloc = [&](size_t bytes) {
        void* p = ws + off;
        off += bytes;
        off = (off + 63) & ~(size_t)63;
        return p;
    };
    unsigned char* pcnt = (unsigned char*)alloc((size_t)KC * N);  // counts->coff
    int*    rowptr  = (int*)alloc((size_t)(N + 1) * 4);   // local prefixes
    int*    rowptr2 = (int*)alloc((size_t)(N + 1) * 4);   // corrected (agg uses)
    int*    csr     = (int*)alloc((size_t)E * 4);
    float*  dinv    = (float*)alloc((size_t)N * 4);
    int*    bsum    = (int*)alloc((size_t)256 * 4);
    __half* WT1     = (__half*)alloc((size_t)NF * NF * 2);
    __half* WT2     = (__half*)alloc((size_t)NF * NF * 2);
    __half* H16     = (__half*)alloc((size_t)N * NF * 2);
    __half* A16     = (__half*)alloc((size_t)N * NF * 2);

    int nb  = (N + 255) / 256;                 // 196 (<=256)
    int Ec  = (((E + KC - 1) / KC) + 3) & ~3;  // chunk size, multiple of 4
    int GB2 = (N + 127) / 128;                 // gemm1 blocks (512 thr)
    int sb  = (N + 3) / 4;                     // bsort blocks (4 nodes each)
    int fb  = (N + 15) / 16;                   // agg blocks (16 nodes each)

    count2_k<<<KC * NPART, 512, 0, stream>>>(dst, pcnt, E, N, Ec);
    pscan2_k<<<nb + 128, 256, 0, stream>>>(pcnt, dinv, rowptr, bsum, N, N, nb,
                                           W1, W2, WT1, WT2);
    mid_k<<<GB2 + KC * NPART, 512, 0, stream>>>(src, dst, rowptr, pcnt, bsum,
                                                rowptr2, csr, E, N, Ec, nb,
                                                x, WT1, dinv, H16, GB2);
    // sort each bucket by src so concurrent waves sweep src-space coherently
    bsort_k<<<sb, 256, 0, stream>>>(rowptr2, csr, N);
    // fused layer-1 aggregate + layer-2 GEMM (writes A16 = dinv-scaled L2 feats)
    aggmm_k<<<fb, 256, 0, stream>>>(H16, rowptr2, csr, dinv, b1, WT2, A16, N);
    // final aggregate -> fp32 output
    agg4_k<<<fb, 256, 0, stream>>>(A16, rowptr2, csr, dinv, b2, out, N);
}

// Round 3
// 227.589 us; speedup vs baseline: 1.0250x; 1.0250x over previous
//
#include <hip/hip_runtime.h>
#include <hip/hip_fp16.h>

#define NF 128    // feature dim, fixed by the problem
#define KC 64     // edge chunks
#define NPART 4   // node partitions (N/4 ints must fit LDS: 12500*4B = 50KB)
#define NPMAX 12544

typedef _Float16 half8  __attribute__((ext_vector_type(8)));
typedef _Float16 half4v __attribute__((ext_vector_type(4)));
typedef float    floatx4 __attribute__((ext_vector_type(4)));

// ---------------- count2: LDS histogram per (chunk, partition) -------------------
__global__ __launch_bounds__(512) void count2_k(
    const int* __restrict__ dst, unsigned char* __restrict__ pcnt,
    int E, int N, int Ec)
{
    __shared__ int lcnt[NPMAX];
    const int p = blockIdx.x & 3, c = blockIdx.x >> 2;
    const int Np = (N + 3) >> 2;
    const int lo = p * Np, hi = min(lo + Np, N);
    const int sz = hi - lo;
    for (int i = threadIdx.x; i < sz; i += 512) lcnt[i] = 0;
    __syncthreads();

    const int e0 = c * Ec, e1 = min(e0 + Ec, E);
    for (int e = e0 + (int)threadIdx.x * 4; e + 3 < e1; e += 512 * 4) {
        int4 d = *(const int4*)(dst + e);
        if (d.x >= lo && d.x < hi) atomicAdd(&lcnt[d.x - lo], 1);
        if (d.y >= lo && d.y < hi) atomicAdd(&lcnt[d.y - lo], 1);
        if (d.z >= lo && d.z < hi) atomicAdd(&lcnt[d.z - lo], 1);
        if (d.w >= lo && d.w < hi) atomicAdd(&lcnt[d.w - lo], 1);
    }
    int rem0 = e0 + ((e1 - e0) & ~3);
    for (int e = rem0 + (int)threadIdx.x; e < e1; e += 512) {
        int d = dst[e];
        if (d >= lo && d < hi) atomicAdd(&lcnt[d - lo], 1);
    }
    __syncthreads();
    for (int i = threadIdx.x; i < sz; i += 512)
        pcnt[(size_t)c * N + lo + i] = (unsigned char)lcnt[i];
}

// ---------------- pscan2 (+fused W-transpose) ------------------------------------
__global__ __launch_bounds__(256) void pscan2_k(
    unsigned char* __restrict__ pcnt, float* __restrict__ dinv,
    int* __restrict__ rowptr, int* __restrict__ blocksum, int n, int N, int nb,
    const float* __restrict__ W1, const float* __restrict__ W2,
    __half* __restrict__ WT1, __half* __restrict__ WT2)
{
    if ((int)blockIdx.x >= nb) {
        int idx = ((int)blockIdx.x - nb) * 256 + threadIdx.x;   // 0..32767
        const float* W = (idx < 16384) ? W1 : W2;
        __half* WT     = (idx < 16384) ? WT1 : WT2;
        int j = idx & 16383;
        int nn = j & 127, k = j >> 7;
        WT[nn * NF + k] = __float2half(W[k * NF + nn]);
        return;
    }
    __shared__ int sm[256];
    int tid = threadIdx.x;
    int bin = blockIdx.x * 256 + tid;
    int total = 0;
    if (bin < n) {
        #pragma unroll 4
        for (int c = 0; c < KC; c++) {
            size_t o = (size_t)c * N + bin;
            int v = pcnt[o];
            pcnt[o] = (unsigned char)total;   // exclusive chunk prefix (coff)
            total += v;
        }
        dinv[bin] = rsqrtf((float)total + 1.0f);  // +1 = self-loop
    }
    sm[tid] = total;
    __syncthreads();
    #pragma unroll
    for (int d = 1; d < 256; d <<= 1) {
        int t = (tid >= d) ? sm[tid - d] : 0;
        __syncthreads();
        sm[tid] += t;
        __syncthreads();
    }
    if (bin < n) rowptr[bin] = sm[tid] - total;    // local exclusive prefix
    if (tid == 255) blocksum[blockIdx.x] = sm[255];
}

// ---------------- MFMA GEMM body (512 threads, 128 rows/block) -------------------
template<bool F32IN>
__device__ __forceinline__ void gemm_body512(
    const void* __restrict__ Xv, const __half* __restrict__ WT,
    const float* __restrict__ dinv, __half* __restrict__ out, int M, int bid,
    __half (*wlds)[136])
{
    const int tid = threadIdx.x;
    {   // stage WT (128x128 halves): 4 threads/row, 32 halves each
        int r = tid >> 2;
        int c0 = (tid & 3) * 32;
        const half8* s = (const half8*)(WT + (size_t)r * NF + c0);
        half8* d = (half8*)&wlds[r][c0];
        #pragma unroll
        for (int j = 0; j < 4; j++) d[j] = s[j];
    }
    __syncthreads();

    const int wave = tid >> 6, lane = tid & 63;
    const int quad = lane >> 4, l15 = lane & 15;
    const int rowA = bid * 128 + wave * 16 + l15;
    const int rowc = (rowA < M) ? rowA : (M - 1);

    half8 afr[4];
    if (F32IN) {
        const float* X = (const float*)Xv;
        #pragma unroll
        for (int kc = 0; kc < 4; kc++) {
            const floatx4* p = (const floatx4*)(X + (size_t)rowc * NF + kc * 32 + quad * 8);
            floatx4 u = p[0], v = p[1];
            half8 a;
            a[0] = (_Float16)u[0]; a[1] = (_Float16)u[1];
            a[2] = (_Float16)u[2]; a[3] = (_Float16)u[3];
            a[4] = (_Float16)v[0]; a[5] = (_Float16)v[1];
            a[6] = (_Float16)v[2]; a[7] = (_Float16)v[3];
            afr[kc] = a;
        }
    } else {
        const __half* X = (const __half*)Xv;
        #pragma unroll
        for (int kc = 0; kc < 4; kc++)
            afr[kc] = *(const half8*)(X + (size_t)rowc * NF + kc * 32 + quad * 8);
    }

    floatx4 acc[8];
    #pragma unroll
    for (int ct = 0; ct < 8; ct++) { floatx4 z = {0.f, 0.f, 0.f, 0.f}; acc[ct] = z; }

    #pragma unroll
    for (int kc = 0; kc < 4; kc++) {
        #pragma unroll
        for (int ct = 0; ct < 8; ct++) {
            half8 b = *(const half8*)&wlds[ct * 16 + l15][kc * 32 + quad * 8];
            acc[ct] = __builtin_amdgcn_mfma_f32_16x16x32_f16(afr[kc], b, acc[ct], 0, 0, 0);
        }
    }

    const int orow0 = bid * 128 + wave * 16 + quad * 4;
    #pragma unroll
    for (int r = 0; r < 4; r++) {
        int orow = orow0 + r;
        if (orow < M) {
            float s = dinv[orow];
            #pragma unroll
            for (int ct = 0; ct < 8; ct++)
                out[(size_t)orow * NF + ct * 16 + l15] = __float2half(acc[ct][r] * s);
        }
    }
}

// ---------------- mid_k: fused gemm1 + fill (+add_off) ---------------------------
__global__ __launch_bounds__(512) void mid_k(
    const int* __restrict__ src, const int* __restrict__ dst,
    const int* __restrict__ rowptr, const unsigned char* __restrict__ coff,
    const int* __restrict__ blocksum, int* __restrict__ rowptr2,
    int* __restrict__ csr, int E, int N, int Ec, int nb,
    const float* __restrict__ X, const __half* __restrict__ WT,
    const float* __restrict__ dinv, __half* __restrict__ H, int GB2)
{
    __shared__ __align__(16) char smem[NPMAX * 4 + 1024];   // 51.2KB union
    const int tid = threadIdx.x;
    if ((int)blockIdx.x < GB2) {
        gemm_body512<true>(X, WT, dinv, H, N, blockIdx.x, (__half(*)[136])smem);
        return;
    }
    int* lcur = (int*)smem;
    int* pref = (int*)(smem + NPMAX * 4);

    const int b = blockIdx.x - GB2;
    const int p = b & 3, c = b >> 2;
    const int Np = (N + 3) >> 2;
    const int lo = p * Np, hi = min(lo + Np, N);
    const int sz = hi - lo;

    // exclusive prefix of blocksum[0..nb) in pref
    int v = (tid < nb) ? blocksum[tid] : 0;
    if (tid < 256) pref[tid] = v;
    __syncthreads();
    #pragma unroll
    for (int d = 1; d < 256; d <<= 1) {
        int t = (tid < 256 && tid >= d) ? pref[tid - d] : 0;
        __syncthreads();
        if (tid < 256) pref[tid] += t;
        __syncthreads();
    }
    if (tid < 256) pref[tid] -= v;
    __syncthreads();

    for (int i = tid; i < sz; i += 512) {
        int bin = lo + i;
        int r = rowptr[bin] + pref[bin >> 8] + (int)coff[(size_t)c * N + bin];
        lcur[i] = r;
        if (c == 0) rowptr2[bin] = r;
    }
    if (c == 0 && p == 0 && tid == 0) rowptr2[N] = E;
    __syncthreads();

    const int e0 = c * Ec, e1 = min(e0 + Ec, E);
    for (int e = e0 + tid * 4; e + 3 < e1; e += 512 * 4) {
        int4 d = *(const int4*)(dst + e);
        int4 s = *(const int4*)(src + e);
        if (d.x >= lo && d.x < hi) csr[atomicAdd(&lcur[d.x - lo], 1)] = s.x;
        if (d.y >= lo && d.y < hi) csr[atomicAdd(&lcur[d.y - lo], 1)] = s.y;
        if (d.z >= lo && d.z < hi) csr[atomicAdd(&lcur[d.z - lo], 1)] = s.z;
        if (d.w >= lo && d.w < hi) csr[atomicAdd(&lcur[d.w - lo], 1)] = s.w;
    }
    int rem0 = e0 + ((e1 - e0) & ~3);
    for (int e = rem0 + tid; e < e1; e += 512) {
        int d = dst[e];
        if (d >= lo && d < hi) csr[atomicAdd(&lcur[d - lo], 1)] = src[e];
    }
}

// ---------------- bsort: sort each CSR bucket by src (locality only) -------------
__global__ __launch_bounds__(256) void bsort_k(
    const int* __restrict__ rowptr, int* __restrict__ csr, int n)
{
    int wave = threadIdx.x >> 6, lane = threadIdx.x & 63;
    int node = blockIdx.x * 4 + wave;
    if (node >= n) return;
    int base = rowptr[node], cnt = rowptr[node + 1] - base;
    for (int off = 0; off < cnt; off += 64) {
        int m = min(64, cnt - off);
        if (m <= 1) break;
        int v = (lane < m) ? csr[base + off + lane] : 0x7fffffff;
        #pragma unroll
        for (int k = 2; k <= 64; k <<= 1) {
            #pragma unroll
            for (int j = k >> 1; j >= 1; j >>= 1) {
                int pv = __shfl_xor(v, j, 64);
                bool up = ((lane & k) == 0);
                bool mn = (((lane & j) == 0) == up);
                v = mn ? min(v, pv) : max(v, pv);
            }
        }
        if (lane < m) csr[base + off + lane] = v;
    }
}

// ---------------- gather8s: 8 nodes/wave, lockstep sweep, 16 loads deep ----------
// Buckets sorted by src. Per round: 2 edges of EACH of 8 nodes — all 16 row
// loads issued back-to-back (R13-depth x2) so MLP is preserved, while the
// 2-edge/node/round quantile sweep keeps all resident waves reading the same
// moving src window (the mechanism that cut FETCH 113->86MB in R2). Per-node
// state (base/cnt) is wave-uniform -> SGPRs. Clamped-dup slots re-read a
// just-loaded row (L1 hit).
__device__ __forceinline__ void gather8s(
    const half4v* __restrict__ hs4, const int* __restrict__ csr,
    const int* __restrict__ rowptr, int node0, int n,
    int eg, int fl, int lane, floatx4 acc[8])
{
    int base[8], cc[8], rc[8], idx[8];
    int maxc = 0;
    #pragma unroll
    for (int k = 0; k < 8; k++) {
        int nd = node0 + k;
        int b0 = 0, c0 = 0;
        if (nd < n) { b0 = rowptr[nd]; c0 = rowptr[nd + 1] - b0; }
        base[k] = b0; rc[k] = c0; cc[k] = min(c0, 64);
        maxc = max(maxc, cc[k]);
    }
    #pragma unroll
    for (int k = 0; k < 8; k++)
        idx[k] = (lane < cc[k]) ? __builtin_nontemporal_load(&csr[base[k] + lane]) : 0;

    #pragma unroll
    for (int k = 0; k < 8; k++) { floatx4 z = {0.f, 0.f, 0.f, 0.f}; acc[k] = z; }

    if (eg == 0) {   // self-loops (8 independent loads — also a warm-up batch)
        half4v sv[8];
        #pragma unroll
        for (int k = 0; k < 8; k++) {
            int nd = min(node0 + k, n - 1);
            sv[k] = hs4[(size_t)nd * 32 + fl];
        }
        #pragma unroll
        for (int k = 0; k < 8; k++) {
            if (node0 + k < n) {
                acc[k][0] += (float)sv[k][0]; acc[k][1] += (float)sv[k][1];
                acc[k][2] += (float)sv[k][2]; acc[k][3] += (float)sv[k][3];
            }
        }
    }

    const int rmax = (maxc + 1) >> 1;
    for (int s = 0; s < rmax; s++) {
        const int e2 = s * 2;
        int sidx[8];
        half4v v[8];
        #pragma unroll
        for (int k = 0; k < 8; k++) {
            int ec = min(e2 + eg, cc[k] - 1);
            ec = (ec < 0) ? 0 : ec;
            sidx[k] = __shfl(idx[k], ec, 64);
        }
        #pragma unroll
        for (int k = 0; k < 8; k++)
            v[k] = hs4[(size_t)sidx[k] * 32 + fl];
        #pragma unroll
        for (int k = 0; k < 8; k++) {
            if (e2 + eg < cc[k]) {
                acc[k][0] += (float)v[k][0]; acc[k][1] += (float)v[k][1];
                acc[k][2] += (float)v[k][2]; acc[k][3] += (float)v[k][3];
            }
        }
    }

    // tails (cnt > 64): essentially never at Poisson(16); simple unit-2 walk
    #pragma unroll
    for (int k = 0; k < 8; k++) {
        if (rc[k] > 64) {
            for (int off = 64; off < rc[k]; off += 64) {
                int m = min(64, rc[k] - off);
                int id2 = (lane < m) ? __builtin_nontemporal_load(&csr[base[k] + off + lane]) : 0;
                for (int j = 0; j < m; j += 2) {
                    int si = __shfl(id2, min(j + eg, m - 1), 64);
                    half4v v = hs4[(size_t)si * 32 + fl];
                    if (j + eg < m) {
                        acc[k][0] += (float)v[0]; acc[k][1] += (float)v[1];
                        acc[k][2] += (float)v[2]; acc[k][3] += (float)v[3];
                    }
                }
            }
        }
    }

    #pragma unroll
    for (int k = 0; k < 8; k++) {
        #pragma unroll
        for (int q = 0; q < 4; q++)
            acc[k][q] += __shfl_xor(acc[k][q], 32, 64);
    }
}

// ---------------- aggmm: fused agg(layer1) + gemm2, 32 nodes/block ---------------
__global__ __launch_bounds__(256, 4) void aggmm_k(
    const __half* __restrict__ hs, const int* __restrict__ rowptr,
    const int* __restrict__ csr, const float* __restrict__ dinv,
    const float* __restrict__ bias, const __half* __restrict__ WT,
    __half* __restrict__ Hout, int n)
{
    __shared__ __half alds[32][136];
    const int tid = threadIdx.x;
    const int wave = tid >> 6, lane = tid & 63;
    const int eg = lane >> 5, fl = lane & 31;
    const int nb0 = blockIdx.x * 32;
    const int node0 = nb0 + wave * 8;

    floatx4 acc[8];
    gather8s((const half4v*)hs, csr, rowptr, node0, n, eg, fl, lane, acc);

    if (eg == 0) {
        #pragma unroll
        for (int k = 0; k < 8; k++) {
            int node = node0 + k;
            half4v h;
            if (node < n) {
                float dv = dinv[node];
                h[0] = (_Float16)fmaxf(dv * acc[k][0] + bias[fl * 4 + 0], 0.f);
                h[1] = (_Float16)fmaxf(dv * acc[k][1] + bias[fl * 4 + 1], 0.f);
                h[2] = (_Float16)fmaxf(dv * acc[k][2] + bias[fl * 4 + 2], 0.f);
                h[3] = (_Float16)fmaxf(dv * acc[k][3] + bias[fl * 4 + 3], 0.f);
            } else {
                h[0] = (_Float16)0.f; h[1] = (_Float16)0.f;
                h[2] = (_Float16)0.f; h[3] = (_Float16)0.f;
            }
            *(half4v*)&alds[wave * 8 + k][fl * 4] = h;
        }
    }
    __syncthreads();

    // 32x128 output: wave w owns col-tiles {2w, 2w+1}, both 16-row tiles
    const int quad = lane >> 4, l15 = lane & 15;
    half8 afr0[4], afr1[4];
    #pragma unroll
    for (int kc = 0; kc < 4; kc++) {
        afr0[kc] = *(const half8*)&alds[l15][kc * 32 + quad * 8];
        afr1[kc] = *(const half8*)&alds[16 + l15][kc * 32 + quad * 8];
    }

    floatx4 o00 = {0.f, 0.f, 0.f, 0.f}, o01 = {0.f, 0.f, 0.f, 0.f};
    floatx4 o10 = {0.f, 0.f, 0.f, 0.f}, o11 = {0.f, 0.f, 0.f, 0.f};
    const int ct0 = wave * 2, ct1 = wave * 2 + 1;
    #pragma unroll
    for (int kc = 0; kc < 4; kc++) {
        half8 b0 = *(const half8*)(WT + (size_t)(ct0 * 16 + l15) * NF + kc * 32 + quad * 8);
        half8 b1 = *(const half8*)(WT + (size_t)(ct1 * 16 + l15) * NF + kc * 32 + quad * 8);
        o00 = __builtin_amdgcn_mfma_f32_16x16x32_f16(afr0[kc], b0, o00, 0, 0, 0);
        o01 = __builtin_amdgcn_mfma_f32_16x16x32_f16(afr0[kc], b1, o01, 0, 0, 0);
        o10 = __builtin_amdgcn_mfma_f32_16x16x32_f16(afr1[kc], b0, o10, 0, 0, 0);
        o11 = __builtin_amdgcn_mfma_f32_16x16x32_f16(afr1[kc], b1, o11, 0, 0, 0);
    }

    #pragma unroll
    for (int r = 0; r < 4; r++) {
        int n0 = nb0 + quad * 4 + r;
        int n1 = n0 + 16;
        if (n0 < n) {
            float s = dinv[n0];
            Hout[(size_t)n0 * NF + ct0 * 16 + l15] = __float2half(o00[r] * s);
            Hout[(size_t)n0 * NF + ct1 * 16 + l15] = __float2half(o01[r] * s);
        }
        if (n1 < n) {
            float s = dinv[n1];
            Hout[(size_t)n1 * NF + ct0 * 16 + l15] = __float2half(o10[r] * s);
            Hout[(size_t)n1 * NF + ct1 * 16 + l15] = __float2half(o11[r] * s);
        }
    }
}

// ---------------- agg4: final aggregate (fp32 out), 32 nodes/block ---------------
__global__ __launch_bounds__(256, 4) void agg4_k(
    const __half* __restrict__ hs, const int* __restrict__ rowptr,
    const int* __restrict__ csr, const float* __restrict__ dinv,
    const float* __restrict__ bias, float* __restrict__ outf, int n)
{
    const int tid = threadIdx.x;
    const int wave = tid >> 6, lane = tid & 63;
    const int eg = lane >> 5, fl = lane & 31;
    const int node0 = blockIdx.x * 32 + wave * 8;

    floatx4 acc[8];
    gather8s((const half4v*)hs, csr, rowptr, node0, n, eg, fl, lane, acc);

    if (eg == 0) {
        #pragma unroll
        for (int k = 0; k < 8; k++) {
            int node = node0 + k;
            if (node < n) {
                float dv = dinv[node];
                floatx4 w;
                w[0] = dv * acc[k][0] + bias[fl * 4 + 0];
                w[1] = dv * acc[k][1] + bias[fl * 4 + 1];
                w[2] = dv * acc[k][2] + bias[fl * 4 + 2];
                w[3] = dv * acc[k][3] + bias[fl * 4 + 3];
                *(floatx4*)(outf + (size_t)node * NF + fl * 4) = w;
            }
        }
    }
}

// ---------------- launch ----------------

extern "C" void kernel_launch(void* const* d_in, const int* in_sizes, int n_in,
                              void* d_out, int out_size, void* d_ws, size_t ws_size,
                              hipStream_t stream) {
    const float* x  = (const float*)d_in[0];
    const int*   ei = (const int*)d_in[1];
    const float* W1 = (const float*)d_in[2];
    const float* b1 = (const float*)d_in[3];
    const float* W2 = (const float*)d_in[4];
    const float* b2 = (const float*)d_in[5];
    float* out = (float*)d_out;

    const int N = in_sizes[0] / NF;   // 50000
    const int E = in_sizes[1] / 2;    // 800000
    const int* src = ei;
    const int* dst = ei + E;

    char* ws = (char*)d_ws;
    size_t off = 0;
    auto alloc = [&](size_t bytes) {
        void* p = ws + off;
        off += bytes;
        off = (off + 63) & ~(size_t)63;
        return p;
    };
    unsigned char* pcnt = (unsigned char*)alloc((size_t)KC * N);  // counts->coff
    int*    rowptr  = (int*)alloc((size_t)(N + 1) * 4);   // local prefixes
    int*    rowptr2 = (int*)alloc((size_t)(N + 1) * 4);   // corrected (agg uses)
    int*    csr     = (int*)alloc((size_t)E * 4);
    float*  dinv    = (float*)alloc((size_t)N * 4);
    int*    bsum    = (int*)alloc((size_t)256 * 4);
    __half* WT1     = (__half*)alloc((size_t)NF * NF * 2);
    __half* WT2     = (__half*)alloc((size_t)NF * NF * 2);
    __half* H16     = (__half*)alloc((size_t)N * NF * 2);
    __half* A16     = (__half*)alloc((size_t)N * NF * 2);

    int nb  = (N + 255) / 256;                 // 196 (<=256)
    int Ec  = (((E + KC - 1) / KC) + 3) & ~3;  // chunk size, multiple of 4
    int GB2 = (N + 127) / 128;                 // gemm1 blocks (512 thr)
    int sb  = (N + 3) / 4;                     // bsort blocks (4 nodes each)
    int fb  = (N + 31) / 32;                   // agg blocks (32 nodes each)

    count2_k<<<KC * NPART, 512, 0, stream>>>(dst, pcnt, E, N, Ec);
    pscan2_k<<<nb + 128, 256, 0, stream>>>(pcnt, dinv, rowptr, bsum, N, N, nb,
                                           W1, W2, WT1, WT2);
    mid_k<<<GB2 + KC * NPART, 512, 0, stream>>>(src, dst, rowptr, pcnt, bsum,
                                                rowptr2, csr, E, N, Ec, nb,
                                                x, WT1, dinv, H16, GB2);
    // sort each bucket by src so concurrent waves sweep src-space coherently
    bsort_k<<<sb, 256, 0, stream>>>(rowptr2, csr, N);
    // fused layer-1 aggregate + layer-2 GEMM
    aggmm_k<<<fb, 256, 0, stream>>>(H16, rowptr2, csr, dinv, b1, WT2, A16, N);
    // final aggregate -> fp32 output
    agg4_k<<<fb, 256, 0, stream>>>(A16, rowptr2, csr, dinv, b2, out, N);
}